// Round 9
// baseline (574.297 us; speedup 1.0000x reference)
//
#include <hip/hip_runtime.h>

#define ALPHA 0.2f

typedef __attribute__((ext_vector_type(8))) short short8;
typedef __attribute__((ext_vector_type(4))) float f32x4;

// ---------- helpers ----------
__device__ __forceinline__ unsigned short f2b(float f) {
  // round-to-nearest-even f32 -> bf16 bits
  unsigned int u; __builtin_memcpy(&u, &f, 4);
  unsigned int r = (u + 0x7FFFu + ((u >> 16) & 1u)) >> 16;
  return (unsigned short)r;
}
__device__ __forceinline__ float b2f(unsigned short v) {
  unsigned int u = ((unsigned int)v) << 16; float f; __builtin_memcpy(&f, &u, 4); return f;
}
__device__ __forceinline__ void gl_lds16(const unsigned short* g, unsigned short* l) {
  // async global->LDS, 16B/lane; LDS dst = wave-uniform base + lane*16
  __builtin_amdgcn_global_load_lds((__attribute__((address_space(1))) void*)g,
                                   (__attribute__((address_space(3))) void*)l, 16, 0, 0);
}
__device__ __forceinline__ uint4 pack8(float4 v0, float4 v1) {
  alignas(16) unsigned short o[8];
  o[0] = f2b(v0.x); o[1] = f2b(v0.y); o[2] = f2b(v0.z); o[3] = f2b(v0.w);
  o[4] = f2b(v1.x); o[5] = f2b(v1.y); o[6] = f2b(v1.z); o[7] = f2b(v1.w);
  return *(const uint4*)o;
}

// lane-contiguous fp32->bf16: one coalesced float4 load -> coalesced 8B store
__device__ __forceinline__ void cvt_f4(const float* __restrict__ in,
                                       unsigned short* __restrict__ out,
                                       unsigned int f4idx) {
  float4 v = ((const float4*)in)[f4idx];
  alignas(8) unsigned short o[4];
  o[0] = f2b(v.x); o[1] = f2b(v.y); o[2] = f2b(v.z); o[3] = f2b(v.w);
  ((uint2*)out)[f4idx] = *(const uint2*)o;
}

// ---------- prep1: cvt fcw->bf16 + transpose W + zero f1/f2 ----------
__global__ __launch_bounds__(256) void prep1(const float* __restrict__ fcw,
                                             unsigned short* __restrict__ fcwb,
                                             const float* __restrict__ W,
                                             unsigned short* __restrict__ Wt,
                                             float* __restrict__ f1z,
                                             float* __restrict__ f2z) {
  __shared__ alignas(16) unsigned short tile[64][72];
  unsigned int bx = blockIdx.x;
  unsigned int tid = threadIdx.x;
  if (bx < 256u) {
    unsigned int base = bx * 512u;
    cvt_f4(fcw, fcwb, base + tid);
    cvt_f4(fcw, fcwb, base + 256u + tid);
  } else if (bx < 384u) {
    // W transpose: tile (k0..k0+64) x (n0..n0+64)
    unsigned int idx = bx - 256u;                 // 128 blocks: 16 k-tiles x 8 n-tiles
    unsigned int k0 = (idx >> 3) * 64, n0 = (idx & 7) * 64;
    #pragma unroll
    for (int p = 0; p < 4; p++) {
      int r = p * 16 + (tid >> 4);
      int c = (tid & 15) * 4;
      float4 v = *(const float4*)(W + (size_t)(k0 + r) * 512 + n0 + c);
      tile[r][c] = f2b(v.x); tile[r][c + 1] = f2b(v.y);
      tile[r][c + 2] = f2b(v.z); tile[r][c + 3] = f2b(v.w);
    }
    __syncthreads();
    int f = tid >> 2;
    int ic = (tid & 3) * 16;
    alignas(16) unsigned short buf[16];
    #pragma unroll
    for (int k = 0; k < 16; k++) buf[k] = tile[ic + k][f];
    uint4* dst = (uint4*)(Wt + (size_t)(n0 + f) * 1024 + k0 + ic);
    dst[0] = ((const uint4*)buf)[0];
    dst[1] = ((const uint4*)buf)[1];
  } else {
    // zero f1/f2 (16384 floats each... actually 16384 rows) -> 16K floats each
    float4 z = {0.f, 0.f, 0.f, 0.f};
    #pragma unroll
    for (int i = 0; i < 16; i++) ((float4*)f1z)[i * 256 + tid] = z;
    #pragma unroll
    for (int i = 0; i < 16; i++) ((float4*)f2z)[i * 256 + tid] = z;
  }
}

// ---------- rowsum + P in one pass, reading adj DIRECTLY ----------
__global__ __launch_bounds__(256) void rowsum_P(const int* __restrict__ adj,
                                                const float* __restrict__ f1,
                                                const float* __restrict__ f2,
                                                float* __restrict__ invl,
                                                unsigned short* __restrict__ P) {
  int row = blockIdx.x * 4 + (threadIdx.x >> 6);
  int lane = threadIdx.x & 63;
  int b = row >> 10;
  float f1v = f1[row];
  const int4* ap = (const int4*)(adj + (size_t)row * 1024) + lane * 4;
  int4 a0 = ap[0];
  int4 a1 = ap[1];
  int4 a2 = ap[2];
  int4 a3 = ap[3];
  int av[16] = {a0.x, a0.y, a0.z, a0.w, a1.x, a1.y, a1.z, a1.w,
                a2.x, a2.y, a2.z, a2.w, a3.x, a3.y, a3.z, a3.w};
  const float* f2p = f2 + (b << 10) + lane * 16;
  float4 v0 = ((const float4*)f2p)[0];
  float4 v1 = ((const float4*)f2p)[1];
  float4 v2 = ((const float4*)f2p)[2];
  float4 v3 = ((const float4*)f2p)[3];
  float fv[16] = {v0.x, v0.y, v0.z, v0.w, v1.x, v1.y, v1.z, v1.w,
                  v2.x, v2.y, v2.z, v2.w, v3.x, v3.y, v3.z, v3.w};
  float s = 0.f;
  alignas(16) unsigned short o[16];
  #pragma unroll
  for (int j = 0; j < 16; j++) {
    float p = 0.f;
    if (av[j] > 0) {
      float z = f1v + fv[j];
      z = z > 0.f ? z : ALPHA * z;
      p = __expf(z);
      s += p;
    }
    o[j] = f2b(p);
  }
  uint4* dst = (uint4*)(P + (size_t)row * 1024 + lane * 16);
  dst[0] = ((const uint4*)o)[0];
  dst[1] = ((const uint4*)o)[1];
  #pragma unroll
  for (int off = 32; off > 0; off >>= 1) s += __shfl_down(s, off);
  if (lane == 0) invl[row] = 1.0f / s;
}

// ---------- bf16 GEMM: C(MxN) = A(MxK) @ Bt(NxK)^T ----------
// BM=128, BN=256, BK=64; 512 threads = 8 waves (2m x 4n), wave tile 64x64
// (acc[4][4], 32 MFMA/wave/K-step). Grid = 256 blocks = 1/CU.
// SINGLE-buffered 48KB LDS -> 2 blocks/CU (16 waves/CU): m114 cross-block
// overlap covers the stage drain. Loop: read frags -> sync (buffer free) ->
// issue stage(k+1) into same buffer -> MFMA (covers load flight) -> sync.
// Plain __syncthreads everywhere (compiler emits the vm/lgkm drains).
// CVTA=1 (GEMM1): A is fp32 (x); A(k+1) via 4 float4 reg loads issued with
// B's gl_lds, pack8+ds_write after MFMA (16 VGPR transient, within-iter).
// XOR-swizzled LDS: logical (row, colblk cb) at physical cb^(row&7).
// EPI 1: bf16 out at [m][ocol+n], + f1/f2 partials (atomicAdd, a via `scale`),
//        + ht[b][f][i]=C^T via two-pass LDS retile
// EPI 2: fp32 out, +bias, ELU
// EPI 3: bf16 out, * scale[row]
template <int EPI, int CVTA>
__global__ __launch_bounds__(512, 4) void gemm_bt(
    const void* __restrict__ A_, size_t aBS,
    const unsigned short* __restrict__ Bt, size_t bBS,
    int K,
    void* __restrict__ outp, size_t oBS, int ldo, int ocol,
    const float* __restrict__ scale,
    const float* __restrict__ bias,
    unsigned short* __restrict__ htout,
    float* __restrict__ f1g, float* __restrict__ f2g) {
  __shared__ alignas(16) unsigned short smem[24576];        // 48KB
  unsigned short* As = smem;                                 // 128x64
  unsigned short* Bs = smem + 8192;                          // 256x64
  const int tid = threadIdx.x;
  const int lane = tid & 63;
  const int w = tid >> 6;                   // 0..7
  const int m0 = blockIdx.x * 128;
  const int n0 = blockIdx.y * 256;
  const int zb = blockIdx.z;
  const unsigned short* Btb = Bt + (size_t)zb * bBS;

  f32x4 acc[4][4];
  #pragma unroll
  for (int i = 0; i < 4; i++)
    #pragma unroll
    for (int j = 0; j < 4; j++)
      #pragma unroll
      for (int r = 0; r < 4; r++) acc[i][j][r] = 0.f;

  // staging: call t covers rows t*64 + w*8 + (0..7); lane L -> row +L/8,
  // swizzled global col-block (L&7)^(L/8)
  const int lr = lane >> 3;
  const int lc = (lane & 7) ^ lr;
  const unsigned short* ag = nullptr;
  const float* agf = nullptr;
  if (CVTA)
    agf = (const float*)A_ + (size_t)(m0 + w * 8 + lr) * K + lc * 8;
  else
    ag = (const unsigned short*)A_ + (size_t)zb * aBS + (size_t)(m0 + w * 8 + lr) * K + lc * 8;
  const unsigned short* bg = Btb + (size_t)(n0 + w * 8 + lr) * K + lc * 8;
  const int sb = w * 512;                   // wave LDS base within each 64-row half
  const int aw = sb + lane * 8;             // per-lane A ds_write dst (linear = swz)

  const int wm = (w & 1) * 64;              // 2 m-halves
  const int wn = (w >> 1) * 64;             // 4 n-quarters of 256
  const int row16 = lane & 15;
  const int quad = lane >> 4;
  const int sw = row16 & 7;                 // fragment-read swizzle
  const int nk = K >> 6;

  // ---- prologue: stage tile 0 ----
  if (CVTA) {
    float4 av[2][2];
    #pragma unroll
    for (int t = 0; t < 2; t++) {
      av[t][0] = *(const float4*)(agf + (size_t)(t * 64) * K);
      av[t][1] = *(const float4*)(agf + (size_t)(t * 64) * K + 4);
    }
    #pragma unroll
    for (int t = 0; t < 4; t++)
      gl_lds16(bg + (size_t)(t * 64) * K, Bs + t * 4096 + sb);
    #pragma unroll
    for (int t = 0; t < 2; t++)
      *(uint4*)(As + t * 4096 + aw) = pack8(av[t][0], av[t][1]);
  } else {
    #pragma unroll
    for (int t = 0; t < 2; t++)
      gl_lds16(ag + (size_t)(t * 64) * K, As + t * 4096 + sb);
    #pragma unroll
    for (int t = 0; t < 4; t++)
      gl_lds16(bg + (size_t)(t * 64) * K, Bs + t * 4096 + sb);
  }
  __syncthreads();                          // tile 0 visible

  for (int k = 0; k < nk; k++) {
    // read ALL fragments of tile k into registers
    short8 af[2][4], bf[2][4];
    #pragma unroll
    for (int s = 0; s < 2; s++) {
      #pragma unroll
      for (int i = 0; i < 4; i++) {
        af[s][i] = *(const short8*)(As + (wm + i * 16 + row16) * 64 + ((s * 4 + quad) ^ sw) * 8);
        bf[s][i] = *(const short8*)(Bs + (wn + i * 16 + row16) * 64 + ((s * 4 + quad) ^ sw) * 8);
      }
    }
    __syncthreads();                        // reads drained; buffer free

    const bool st = (k + 1 < nk);
    float4 av[2][2];
    if (st) {                               // issue stage of tile k+1
      const int ko = (k + 1) * 64;
      if (CVTA) {
        #pragma unroll
        for (int t = 0; t < 2; t++) {
          av[t][0] = *(const float4*)(agf + ko + (size_t)(t * 64) * K);
          av[t][1] = *(const float4*)(agf + ko + (size_t)(t * 64) * K + 4);
        }
      } else {
        #pragma unroll
        for (int t = 0; t < 2; t++)
          gl_lds16(ag + ko + (size_t)(t * 64) * K, As + t * 4096 + sb);
      }
      #pragma unroll
      for (int t = 0; t < 4; t++)
        gl_lds16(bg + ko + (size_t)(t * 64) * K, Bs + t * 4096 + sb);
    }

    #pragma unroll
    for (int s = 0; s < 2; s++)
      #pragma unroll
      for (int am = 0; am < 4; am++)
        #pragma unroll
        for (int bn = 0; bn < 4; bn++)
          acc[am][bn] = __builtin_amdgcn_mfma_f32_16x16x32_bf16(af[s][am], bf[s][bn], acc[am][bn], 0, 0, 0);

    if (st && CVTA) {                       // cvt+ds_write A(k+1) after MFMA
      #pragma unroll
      for (int t = 0; t < 2; t++)
        *(uint4*)(As + t * 4096 + aw) = pack8(av[t][0], av[t][1]);
    }
    __syncthreads();                        // tile k+1 visible
  }

  // C/D layout: col = lane&15, row = (lane>>4)*4 + reg  [m89/m91-verified]
  const int col = lane & 15;
  const int r0 = quad * 4;
  #pragma unroll
  for (int am = 0; am < 4; am++) {
    #pragma unroll
    for (int bn = 0; bn < 4; bn++) {
      #pragma unroll
      for (int r = 0; r < 4; r++) {
        int m = m0 + wm + am * 16 + r0 + r;
        int n = n0 + wn + bn * 16 + col;
        float v = acc[am][bn][r];
        if (EPI == 3) v *= scale[zb * 1024 + m];
        if (EPI == 2) {
          v += bias[n];
          v = v > 0.f ? v : expm1f(v);   // ELU, alpha=1
          ((float*)outp)[(size_t)m * ldo + n] = v;
        } else {
          ((unsigned short*)outp)[(size_t)zb * oBS + (size_t)m * ldo + ocol + n] = f2b(v);
        }
      }
    }
  }

  if (EPI == 1) {
    // ---- f1/f2 partials from the bf16-rounded h (bit-identical to prep2) ----
    // scale = a: a1 = a[n], a2 = a[512+n]
    float* fbuf = (float*)smem;             // 256 floats: f1loc[128], f2loc[128]
    if (tid < 256) fbuf[tid] = 0.f;
    __syncthreads();
    float a1v[4], a2v[4];
    #pragma unroll
    for (int bn = 0; bn < 4; bn++) {
      int n = n0 + wn + bn * 16 + col;
      a1v[bn] = scale[n];
      a2v[bn] = scale[512 + n];
    }
    float p1[16], p2[16];
    #pragma unroll
    for (int am = 0; am < 4; am++)
      #pragma unroll
      for (int r = 0; r < 4; r++) {
        float s1 = 0.f, s2 = 0.f;
        #pragma unroll
        for (int bn = 0; bn < 4; bn++) {
          float hb = b2f(f2b(acc[am][bn][r]));
          s1 += hb * a1v[bn];
          s2 += hb * a2v[bn];
        }
        p1[am * 4 + r] = s1;
        p2[am * 4 + r] = s2;
      }
    #pragma unroll
    for (int mask = 1; mask < 16; mask <<= 1)
      #pragma unroll
      for (int e = 0; e < 16; e++) {
        p1[e] += __shfl_xor(p1[e], mask);
        p2[e] += __shfl_xor(p2[e], mask);
      }
    if ((lane & 15) == 0) {                 // one lane per quad holds col-sums
      #pragma unroll
      for (int am = 0; am < 4; am++)
        #pragma unroll
        for (int r = 0; r < 4; r++) {
          int ml = wm + am * 16 + r0 + r;
          atomicAdd(&fbuf[ml], p1[am * 4 + r]);
          atomicAdd(&fbuf[128 + ml], p2[am * 4 + r]);
        }
    }
    __syncthreads();
    if (tid < 128) atomicAdd(&f1g[m0 + tid], fbuf[tid]);
    else if (tid < 256) atomicAdd(&f2g[m0 + tid - 128], fbuf[tid]);
    __syncthreads();

    // ---- ht[b][f][i] = C^T via two-pass LDS retile ([128 n][136 stride]) ----
    const int b = m0 >> 10;
    const int i0 = m0 & 1023;
    #pragma unroll
    for (int pass = 0; pass < 2; pass++) {
      if ((wn >> 7) == pass) {              // waves with wn in this 128-half
        int nl = wn & 127;
        #pragma unroll
        for (int am = 0; am < 4; am++)
          #pragma unroll
          for (int bn = 0; bn < 4; bn++)
            #pragma unroll
            for (int r = 0; r < 4; r++) {
              int nloc = nl + bn * 16 + col;
              int mloc = wm + am * 16 + r0 + r;
              smem[nloc * 136 + mloc] = f2b(acc[am][bn][r]);
            }
      }
      __syncthreads();
      #pragma unroll
      for (int p = 0; p < 4; p++) {
        int fr = p * 32 + (tid >> 4);
        int ib = (tid & 15) * 8;
        uint4 v = *(const uint4*)(smem + fr * 136 + ib);
        *(uint4*)(htout + ((size_t)(b * 512 + n0 + pass * 128 + fr) << 10) + i0 + ib) = v;
      }
      __syncthreads();
    }
  }
}

// ---------- launch ----------
extern "C" void kernel_launch(void* const* d_in, const int* in_sizes, int n_in,
                              void* d_out, int out_size, void* d_ws, size_t ws_size,
                              hipStream_t stream) {
  const float* x   = (const float*)d_in[0];  // (16,1024,1024)
  const int*   adj = (const int*)d_in[1];    // (16,1024,1024)
  const float* W   = (const float*)d_in[2];  // (1024,512)
  const float* a   = (const float*)d_in[3];  // (1024,1)
  const float* fcw = (const float*)d_in[4];  // (512,1024)  == Bt layout for GEMM3
  const float* fcb = (const float*)d_in[5];  // (512,)
  float* out = (float*)d_out;                // (16,1024,512) fp32
  char* ws = (char*)d_ws;

  // ws layout (~84.2 MiB)
  unsigned short* P    = (unsigned short*)(ws);               // 32MB P~ bf16
  unsigned short* hp   = (unsigned short*)(ws + 33554432);    // 32MB [agg | h] bf16 rows
  unsigned short* ht   = (unsigned short*)(ws + 67108864);    // 16MB h^T per batch
  unsigned short* Wt   = (unsigned short*)(ws + 83886080);    // 1MB
  unsigned short* fcwb = (unsigned short*)(ws + 84934656);    // 1MB
  float* f1            = (float*)(ws + 85983232);             // 64KB
  float* f2            = (float*)(ws + 86048768);             // 64KB
  float* invl          = (float*)(ws + 86114304);             // 64KB

  // 1: tiny prep (fcw cvt + W transpose + zero f1/f2)
  prep1<<<385, 256, 0, stream>>>(fcw, fcwb, W, Wt, f1, f2);

  // 2: GEMM1  h = x @ W -> hp[:,512:1024] + ht + f1/f2 (all fused)
  gemm_bt<1, 1><<<dim3(128, 2, 1), 512, 0, stream>>>(x, 0, Wt, 0, 1024,
                                                     hp, 0, 1024, 512, a, nullptr,
                                                     ht, f1, f2);
  // 3: P~ (unnormalized, bf16) + 1/rowsum   (reads adj directly)
  rowsum_P<<<4096, 256, 0, stream>>>(adj, f1, f2, invl, P);

  // 4: GEMM2 (per batch): agg = (P~ @ h) * invl  -> hp[:,0:512]
  gemm_bt<3, 0><<<dim3(8, 2, 16), 512, 0, stream>>>(P, 1024 * 1024, ht, 512 * 1024, 1024,
                                                    hp, 1024 * 1024, 1024, 0, invl, nullptr,
                                                    nullptr, nullptr, nullptr);
  // 5: GEMM3: out = elu([agg|h] @ fc_w^T + b)
  gemm_bt<2, 0><<<dim3(128, 2, 1), 512, 0, stream>>>(hp, 0, fcwb, 0, 1024,
                                                     out, 0, 512, 0, nullptr, fcb,
                                                     nullptr, nullptr, nullptr);
}

// Round 10
// 250.846 us; speedup vs baseline: 2.2894x; 2.2894x over previous
//
#include <hip/hip_runtime.h>

#define ALPHA 0.2f

typedef __attribute__((ext_vector_type(8))) short short8;
typedef __attribute__((ext_vector_type(4))) float f32x4;

// ---------- helpers ----------
__device__ __forceinline__ unsigned short f2b(float f) {
  // round-to-nearest-even f32 -> bf16 bits
  unsigned int u; __builtin_memcpy(&u, &f, 4);
  unsigned int r = (u + 0x7FFFu + ((u >> 16) & 1u)) >> 16;
  return (unsigned short)r;
}
__device__ __forceinline__ float b2f(unsigned short v) {
  unsigned int u = ((unsigned int)v) << 16; float f; __builtin_memcpy(&f, &u, 4); return f;
}
__device__ __forceinline__ void gl_lds16(const unsigned short* g, unsigned short* l) {
  // async global->LDS, 16B/lane; LDS dst = wave-uniform base + lane*16
  __builtin_amdgcn_global_load_lds((__attribute__((address_space(1))) void*)g,
                                   (__attribute__((address_space(3))) void*)l, 16, 0, 0);
}
__device__ __forceinline__ uint4 pack8(float4 v0, float4 v1) {
  alignas(16) unsigned short o[8];
  o[0] = f2b(v0.x); o[1] = f2b(v0.y); o[2] = f2b(v0.z); o[3] = f2b(v0.w);
  o[4] = f2b(v1.x); o[5] = f2b(v1.y); o[6] = f2b(v1.z); o[7] = f2b(v1.w);
  return *(const uint4*)o;
}

// lane-contiguous fp32->bf16: one coalesced float4 load -> coalesced 8B store
__device__ __forceinline__ void cvt_f4(const float* __restrict__ in,
                                       unsigned short* __restrict__ out,
                                       unsigned int f4idx) {
  float4 v = ((const float4*)in)[f4idx];
  alignas(8) unsigned short o[4];
  o[0] = f2b(v.x); o[1] = f2b(v.y); o[2] = f2b(v.z); o[3] = f2b(v.w);
  ((uint2*)out)[f4idx] = *(const uint2*)o;
}

// ---------- prep1: cvt fcw->bf16 + transpose W + zero f1/f2 ----------
__global__ __launch_bounds__(256) void prep1(const float* __restrict__ fcw,
                                             unsigned short* __restrict__ fcwb,
                                             const float* __restrict__ W,
                                             unsigned short* __restrict__ Wt,
                                             float* __restrict__ f1z,
                                             float* __restrict__ f2z) {
  __shared__ alignas(16) unsigned short tile[64][72];
  unsigned int bx = blockIdx.x;
  unsigned int tid = threadIdx.x;
  if (bx < 256u) {
    unsigned int base = bx * 512u;
    cvt_f4(fcw, fcwb, base + tid);
    cvt_f4(fcw, fcwb, base + 256u + tid);
  } else if (bx < 384u) {
    // W transpose: tile (k0..k0+64) x (n0..n0+64)
    unsigned int idx = bx - 256u;                 // 128 blocks: 16 k-tiles x 8 n-tiles
    unsigned int k0 = (idx >> 3) * 64, n0 = (idx & 7) * 64;
    #pragma unroll
    for (int p = 0; p < 4; p++) {
      int r = p * 16 + (tid >> 4);
      int c = (tid & 15) * 4;
      float4 v = *(const float4*)(W + (size_t)(k0 + r) * 512 + n0 + c);
      tile[r][c] = f2b(v.x); tile[r][c + 1] = f2b(v.y);
      tile[r][c + 2] = f2b(v.z); tile[r][c + 3] = f2b(v.w);
    }
    __syncthreads();
    int f = tid >> 2;
    int ic = (tid & 3) * 16;
    alignas(16) unsigned short buf[16];
    #pragma unroll
    for (int k = 0; k < 16; k++) buf[k] = tile[ic + k][f];
    uint4* dst = (uint4*)(Wt + (size_t)(n0 + f) * 1024 + k0 + ic);
    dst[0] = ((const uint4*)buf)[0];
    dst[1] = ((const uint4*)buf)[1];
  } else {
    // zero f1/f2 (16K floats each)
    float4 z = {0.f, 0.f, 0.f, 0.f};
    #pragma unroll
    for (int i = 0; i < 16; i++) ((float4*)f1z)[i * 256 + tid] = z;
    #pragma unroll
    for (int i = 0; i < 16; i++) ((float4*)f2z)[i * 256 + tid] = z;
  }
}

// ---------- rowsum + P in one pass, reading adj DIRECTLY ----------
__global__ __launch_bounds__(256) void rowsum_P(const int* __restrict__ adj,
                                                const float* __restrict__ f1,
                                                const float* __restrict__ f2,
                                                float* __restrict__ invl,
                                                unsigned short* __restrict__ P) {
  int row = blockIdx.x * 4 + (threadIdx.x >> 6);
  int lane = threadIdx.x & 63;
  int b = row >> 10;
  float f1v = f1[row];
  const int4* ap = (const int4*)(adj + (size_t)row * 1024) + lane * 4;
  int4 a0 = ap[0];
  int4 a1 = ap[1];
  int4 a2 = ap[2];
  int4 a3 = ap[3];
  int av[16] = {a0.x, a0.y, a0.z, a0.w, a1.x, a1.y, a1.z, a1.w,
                a2.x, a2.y, a2.z, a2.w, a3.x, a3.y, a3.z, a3.w};
  const float* f2p = f2 + (b << 10) + lane * 16;
  float4 v0 = ((const float4*)f2p)[0];
  float4 v1 = ((const float4*)f2p)[1];
  float4 v2 = ((const float4*)f2p)[2];
  float4 v3 = ((const float4*)f2p)[3];
  float fv[16] = {v0.x, v0.y, v0.z, v0.w, v1.x, v1.y, v1.z, v1.w,
                  v2.x, v2.y, v2.z, v2.w, v3.x, v3.y, v3.z, v3.w};
  float s = 0.f;
  alignas(16) unsigned short o[16];
  #pragma unroll
  for (int j = 0; j < 16; j++) {
    float p = 0.f;
    if (av[j] > 0) {
      float z = f1v + fv[j];
      z = z > 0.f ? z : ALPHA * z;
      p = __expf(z);
      s += p;
    }
    o[j] = f2b(p);
  }
  uint4* dst = (uint4*)(P + (size_t)row * 1024 + lane * 16);
  dst[0] = ((const uint4*)o)[0];
  dst[1] = ((const uint4*)o)[1];
  #pragma unroll
  for (int off = 32; off > 0; off >>= 1) s += __shfl_down(s, off);
  if (lane == 0) invl[row] = 1.0f / s;
}

// ---------- bf16 GEMM: C(MxN) = A(MxK) @ Bt(NxK)^T ----------
// EXACT round-4 loop (best measured: 49us/gemm, VGPR 52, no spill):
// 128x128 tile, BK=64, 512 threads = 8 waves, each 64x32 (acc[4][2]).
// Double-buffered 64KB LDS -> 2 blocks/CU (occupancy 38%). 2-phase:
// prefetch next K-tile before current ds_read+MFMA, one __syncthreads per
// phase. CVTA=1 (GEMM1): A fp32 (x), reg-staged cvt issue-early/write-late
// WITHIN one iteration (16 VGPR transient).
// XOR-swizzled LDS: logical (row, colblk cb) at physical cb^(row&7).
// EPI 1: bf16 out at [m][ocol+n], + f1/f2 partials (atomicAdd; a via `scale`),
//        + ht[b][f][i]=C^T via LDS retile  (both validated in R9)
// EPI 2: fp32 out, +bias, ELU
// EPI 3: bf16 out, * scale[row]
template <int EPI, int CVTA>
__global__ __launch_bounds__(512, 4) void gemm_bt(
    const void* __restrict__ A_, size_t aBS,
    const unsigned short* __restrict__ Bt, size_t bBS,
    int K,
    void* __restrict__ outp, size_t oBS, int ldo, int ocol,
    const float* __restrict__ scale,
    const float* __restrict__ bias,
    unsigned short* __restrict__ htout,
    float* __restrict__ f1g, float* __restrict__ f2g) {
  __shared__ alignas(16) unsigned short smem[32768];        // 64KB
  unsigned short* As = smem;                                 // 2 x 128x64
  unsigned short* Bs = smem + 16384;
  const int tid = threadIdx.x;
  const int lane = tid & 63;
  const int w = tid >> 6;                   // 0..7
  const int m0 = blockIdx.x * 128;
  const int n0 = blockIdx.y * 128;
  const int zb = blockIdx.z;
  const unsigned short* Btb = Bt + (size_t)zb * bBS;

  f32x4 acc[4][2];
  #pragma unroll
  for (int i = 0; i < 4; i++)
    #pragma unroll
    for (int j = 0; j < 2; j++)
      #pragma unroll
      for (int r = 0; r < 4; r++) acc[i][j][r] = 0.f;

  // staging: pass t in {0,1}; wave w covers rows t*64 + w*8 + (0..7);
  // lane L covers 16B of row t*64 + w*8 + L/8, swizzled col-block (L&7)^(L/8)
  const int lr = lane >> 3;                 // row within 8-row group
  const int lc = (lane & 7) ^ lr;           // swizzled global col-block
  const unsigned short* ag = nullptr;
  const float* agf = nullptr;
  if (CVTA)
    agf = (const float*)A_ + (size_t)(m0 + w * 8 + lr) * K + lc * 8;
  else
    ag = (const unsigned short*)A_ + (size_t)zb * aBS + (size_t)(m0 + w * 8 + lr) * K + lc * 8;
  const unsigned short* bg = Btb + (size_t)(n0 + w * 8 + lr) * K + lc * 8;
  const int sb0 = (w * 8) * 64;             // t=0 wave LDS base (shorts)
  const int sb1 = (64 + w * 8) * 64;        // t=1
  const int lofs = lane * 8;                // per-lane LDS dst for reg-staged A

  const int wm = (w & 1) * 64;              // 2 m-halves
  const int wn = (w >> 1) * 32;             // 4 n-quarters
  const int row16 = lane & 15;
  const int quad = lane >> 4;
  const int sw = row16 & 7;                 // fragment-read swizzle

  // prologue: stage tile k0=0 into buffer 0
  if (CVTA) {
    float4 av[2][2];
    #pragma unroll
    for (int t = 0; t < 2; t++) {
      av[t][0] = *(const float4*)(agf + (size_t)(t * 64) * K);
      av[t][1] = *(const float4*)(agf + (size_t)(t * 64) * K + 4);
    }
    gl_lds16(bg, Bs + sb0);
    gl_lds16(bg + (size_t)64 * K, Bs + sb1);
    *(uint4*)(As + sb0 + lofs) = pack8(av[0][0], av[0][1]);
    *(uint4*)(As + sb1 + lofs) = pack8(av[1][0], av[1][1]);
  } else {
    gl_lds16(ag, As + sb0);
    gl_lds16(ag + (size_t)64 * K, As + sb1);
    gl_lds16(bg, Bs + sb0);
    gl_lds16(bg + (size_t)64 * K, Bs + sb1);
  }
  __syncthreads();                          // tile 0 visible

  int bufo = 0;                             // current buffer offset (shorts)
  for (int k0 = 0; k0 < K; k0 += 64) {
    const int nbufo = bufo ^ 8192;
    const bool pf = (k0 + 64 < K);
    float4 av[2][2];
    if (pf) {                               // issue next-tile loads EARLY
      if (CVTA) {
        #pragma unroll
        for (int t = 0; t < 2; t++) {
          av[t][0] = *(const float4*)(agf + (k0 + 64) + (size_t)(t * 64) * K);
          av[t][1] = *(const float4*)(agf + (k0 + 64) + (size_t)(t * 64) * K + 4);
        }
      } else {
        gl_lds16(ag + (k0 + 64), As + nbufo + sb0);
        gl_lds16(ag + (k0 + 64) + (size_t)64 * K, As + nbufo + sb1);
      }
      gl_lds16(bg + (k0 + 64), Bs + nbufo + sb0);
      gl_lds16(bg + (k0 + 64) + (size_t)64 * K, Bs + nbufo + sb1);
    }
    short8 af[2][4], bf[2][2];
    #pragma unroll
    for (int s = 0; s < 2; s++) {
      #pragma unroll
      for (int i = 0; i < 4; i++)
        af[s][i] = *(const short8*)(As + bufo + (wm + i * 16 + row16) * 64 + ((s * 4 + quad) ^ sw) * 8);
      #pragma unroll
      for (int j = 0; j < 2; j++)
        bf[s][j] = *(const short8*)(Bs + bufo + (wn + j * 16 + row16) * 64 + ((s * 4 + quad) ^ sw) * 8);
    }
    #pragma unroll
    for (int s = 0; s < 2; s++)
      #pragma unroll
      for (int am = 0; am < 4; am++)
        #pragma unroll
        for (int bn = 0; bn < 2; bn++)
          acc[am][bn] = __builtin_amdgcn_mfma_f32_16x16x32_bf16(af[s][am], bf[s][bn], acc[am][bn], 0, 0, 0);
    if (pf && CVTA) {                       // write-late: cvt+ds_write after MFMA
      *(uint4*)(As + nbufo + sb0 + lofs) = pack8(av[0][0], av[0][1]);
      *(uint4*)(As + nbufo + sb1 + lofs) = pack8(av[1][0], av[1][1]);
    }
    __syncthreads();                        // prefetch landed; reads of bufo done
    bufo = nbufo;
  }

  // C/D layout: col = lane&15, row = (lane>>4)*4 + reg  [m89/m91-verified]
  const int col = lane & 15;
  const int r0 = quad * 4;
  #pragma unroll
  for (int am = 0; am < 4; am++) {
    #pragma unroll
    for (int bn = 0; bn < 2; bn++) {
      #pragma unroll
      for (int r = 0; r < 4; r++) {
        int m = m0 + wm + am * 16 + r0 + r;
        int n = n0 + wn + bn * 16 + col;
        float v = acc[am][bn][r];
        if (EPI == 3) v *= scale[zb * 1024 + m];
        if (EPI == 2) {
          v += bias[n];
          v = v > 0.f ? v : expm1f(v);   // ELU, alpha=1
          ((float*)outp)[(size_t)m * ldo + n] = v;
        } else {
          ((unsigned short*)outp)[(size_t)zb * oBS + (size_t)m * ldo + ocol + n] = f2b(v);
        }
      }
    }
  }

  if (EPI == 1) {
    // ---- f1/f2 partials from bf16-rounded h (bit-identical to old prep2;
    //      validated R9). scale = a: a1 = a[n], a2 = a[512+n] ----
    float* fbuf = (float*)smem;             // 256 floats
    if (tid < 256) fbuf[tid] = 0.f;
    __syncthreads();
    float a1v[2], a2v[2];
    #pragma unroll
    for (int bn = 0; bn < 2; bn++) {
      int n = n0 + wn + bn * 16 + col;
      a1v[bn] = scale[n];
      a2v[bn] = scale[512 + n];
    }
    float p1[16], p2[16];
    #pragma unroll
    for (int am = 0; am < 4; am++)
      #pragma unroll
      for (int r = 0; r < 4; r++) {
        float s1 = 0.f, s2 = 0.f;
        #pragma unroll
        for (int bn = 0; bn < 2; bn++) {
          float hb = b2f(f2b(acc[am][bn][r]));
          s1 += hb * a1v[bn];
          s2 += hb * a2v[bn];
        }
        p1[am * 4 + r] = s1;
        p2[am * 4 + r] = s2;
      }
    #pragma unroll
    for (int mask = 1; mask < 16; mask <<= 1)
      #pragma unroll
      for (int e = 0; e < 16; e++) {
        p1[e] += __shfl_xor(p1[e], mask);
        p2[e] += __shfl_xor(p2[e], mask);
      }
    if ((lane & 15) == 0) {
      #pragma unroll
      for (int am = 0; am < 4; am++)
        #pragma unroll
        for (int r = 0; r < 4; r++) {
          int ml = wm + am * 16 + r0 + r;
          atomicAdd(&fbuf[ml], p1[am * 4 + r]);
          atomicAdd(&fbuf[128 + ml], p2[am * 4 + r]);
        }
    }
    __syncthreads();
    if (tid < 128) atomicAdd(&f1g[m0 + tid], fbuf[tid]);
    else if (tid < 256) atomicAdd(&f2g[m0 + tid - 128], fbuf[tid]);
    __syncthreads();

    // ---- ht[b][f][i] = C^T via LDS retile ([128 n][136 stride], 35KB) ----
    #pragma unroll
    for (int am = 0; am < 4; am++)
      #pragma unroll
      for (int bn = 0; bn < 2; bn++)
        #pragma unroll
        for (int r = 0; r < 4; r++) {
          int nloc = wn + bn * 16 + col;
          int mloc = wm + am * 16 + r0 + r;
          smem[nloc * 136 + mloc] = f2b(acc[am][bn][r]);
        }
    __syncthreads();
    const int b = m0 >> 10;
    const int i0 = m0 & 1023;
    // 4 iters x 512 thr x 8 shorts = 16384 = 128 f x 128 i (full tile)
    #pragma unroll
    for (int p = 0; p < 4; p++) {
      int fr = p * 32 + (tid >> 4);         // [0,128)
      int ib = (tid & 15) * 8;              // [0,128)
      uint4 v = *(const uint4*)(smem + fr * 136 + ib);
      *(uint4*)(htout + ((size_t)(b * 512 + n0 + fr) << 10) + i0 + ib) = v;
    }
  }
}

// ---------- launch ----------
extern "C" void kernel_launch(void* const* d_in, const int* in_sizes, int n_in,
                              void* d_out, int out_size, void* d_ws, size_t ws_size,
                              hipStream_t stream) {
  const float* x   = (const float*)d_in[0];  // (16,1024,1024)
  const int*   adj = (const int*)d_in[1];    // (16,1024,1024)
  const float* W   = (const float*)d_in[2];  // (1024,512)
  const float* a   = (const float*)d_in[3];  // (1024,1)
  const float* fcw = (const float*)d_in[4];  // (512,1024)  == Bt layout for GEMM3
  const float* fcb = (const float*)d_in[5];  // (512,)
  float* out = (float*)d_out;                // (16,1024,512) fp32
  char* ws = (char*)d_ws;

  // ws layout (~84.2 MiB)
  unsigned short* P    = (unsigned short*)(ws);               // 32MB P~ bf16
  unsigned short* hp   = (unsigned short*)(ws + 33554432);    // 32MB [agg | h] bf16 rows
  unsigned short* ht   = (unsigned short*)(ws + 67108864);    // 16MB h^T per batch
  unsigned short* Wt   = (unsigned short*)(ws + 83886080);    // 1MB
  unsigned short* fcwb = (unsigned short*)(ws + 84934656);    // 1MB
  float* f1            = (float*)(ws + 85983232);             // 64KB
  float* f2            = (float*)(ws + 86048768);             // 64KB
  float* invl          = (float*)(ws + 86114304);             // 64KB

  // 1: tiny prep (fcw cvt + W transpose + zero f1/f2)
  prep1<<<385, 256, 0, stream>>>(fcw, fcwb, W, Wt, f1, f2);

  // 2: GEMM1  h = x @ W -> hp[:,512:1024] + ht + f1/f2 (cvt/transpose/dots fused)
  gemm_bt<1, 1><<<dim3(128, 4, 1), 512, 0, stream>>>(x, 0, Wt, 0, 1024,
                                                     hp, 0, 1024, 512, a, nullptr,
                                                     ht, f1, f2);
  // 3: P~ (unnormalized, bf16) + 1/rowsum   (reads adj directly)
  rowsum_P<<<4096, 256, 0, stream>>>(adj, f1, f2, invl, P);

  // 4: GEMM2 (per batch): agg = (P~ @ h) * invl  -> hp[:,0:512]
  gemm_bt<3, 0><<<dim3(8, 4, 16), 512, 0, stream>>>(P, 1024 * 1024, ht, 512 * 1024, 1024,
                                                    hp, 1024 * 1024, 1024, 0, invl, nullptr,
                                                    nullptr, nullptr, nullptr);
  // 5: GEMM3: out = elu([agg|h] @ fc_w^T + b)
  gemm_bt<2, 0><<<dim3(128, 4, 1), 512, 0, stream>>>(hp, 0, fcwb, 0, 1024,
                                                     out, 0, 512, 0, nullptr, fcb,
                                                     nullptr, nullptr, nullptr);
}